// Round 1
// baseline (783.296 us; speedup 1.0000x reference)
//
#include <hip/hip_runtime.h>

#define H 256
#define NN 128
#define BB 16

typedef __attribute__((ext_vector_type(8))) __bf16 bf16x8;
typedef __attribute__((ext_vector_type(8))) short  s16x8;
typedef __attribute__((ext_vector_type(4))) short  s16x4;
typedef __attribute__((ext_vector_type(4))) float  f32x4;
typedef __attribute__((ext_vector_type(4))) unsigned short u16x4;

__device__ __forceinline__ unsigned short f2b(float f) {
    unsigned u = __float_as_uint(f);
    u = (u + 0x7fffu + ((u >> 16) & 1u)) >> 16;   // RNE fp32 -> bf16
    return (unsigned short)u;
}

__device__ __forceinline__ u16x4 cvt4(f32x4 f) {
    u16x4 w;
    w[0] = f2b(f[0]); w[1] = f2b(f[1]); w[2] = f2b(f[2]); w[3] = f2b(f[3]);
    return w;
}

// K0: WT[k][h] = bf16(W_bin[h][k])  (transpose so B-frag loads are contiguous)
__global__ void k_prep_w(const float* __restrict__ Wb, unsigned short* __restrict__ WT) {
    int k = blockIdx.x;
    int h = threadIdx.x;
    WT[k * H + h] = f2b(Wb[h * H + k]);
}

// K1: xw[r][k] = sum_h inputs[r][h] * W_atom[h][k]   (r = b*128+i, 2048 rows)
__global__ void k_xw(const float* __restrict__ inp, const float* __restrict__ Wa,
                     float* __restrict__ xw) {
    __shared__ float rows[8][H];
    int r0 = blockIdx.x * 8;
    int t = threadIdx.x;
    #pragma unroll
    for (int r = 0; r < 8; ++r) rows[r][t] = inp[(r0 + r) * H + t];
    __syncthreads();
    float acc[8] = {0.f, 0.f, 0.f, 0.f, 0.f, 0.f, 0.f, 0.f};
    for (int h = 0; h < H; ++h) {
        float wv = Wa[h * H + t];
        #pragma unroll
        for (int r = 0; r < 8; ++r) acc[r] += rows[r][h] * wv;
    }
    #pragma unroll
    for (int r = 0; r < 8; ++r) xw[(r0 + r) * H + t] = acc[r];
}

// K2: one block per (b,i). Loops 4 j-tiles of 32 rows, double-buffered LDS,
//     register-staged prefetch so global loads span the compute phase.
//     hidden = relu(binT@WbinT + xw_i + xw_j + b_bin); S_total = sum_j (w.hidden + b_score)
//     ctx[b,i,:] = inp[b,i,:] * S_total   (exclusive owner -> plain store, no atomics)
//     pair[b,i,j,:] = inp_i + inp_j  (nontemporal stores: protect binf residency in L3)
__global__ __launch_bounds__(256, 4) void k_main(
        const float* __restrict__ inp, const float* __restrict__ binf,
        const float* __restrict__ xw, const unsigned short* __restrict__ WT,
        const float* __restrict__ b_bin, const float* __restrict__ w_score,
        const float* __restrict__ b_score,
        float* __restrict__ out_ctx, float* __restrict__ out_pair) {
    __shared__ __align__(16) unsigned short Ab[2][32 * 260];  // 2 x 16.6 KB
    __shared__ __align__(16) float base_l[H];   // xw[b,i,:] + b_bin
    __shared__ __align__(16) float wsc_l[H];
    __shared__ __align__(16) float ini_l[H];    // inputs[b,i,:]
    __shared__ float wred[4];

    int bi = blockIdx.x;            // b*128 + i
    int t  = threadIdx.x;
    int b  = bi >> 7;

    base_l[t] = xw[bi * H + t] + b_bin[t];
    wsc_l[t]  = w_score[t];
    ini_l[t]  = inp[bi * H + t];

    const f32x4* bp = (const f32x4*)(binf + (size_t)bi * NN * H);  // 8192 f32x4 per bi

    f32x4 v[8];

    // ---- prologue: tile 0 -> Ab[0]; issue tile 1 loads ----
    #pragma unroll
    for (int it = 0; it < 8; ++it) v[it] = bp[it * 256 + t];
    #pragma unroll
    for (int it = 0; it < 8; ++it) {
        int idx = it * 256 + t;
        int row = idx >> 6, col = (idx & 63) * 4;
        *(u16x4*)&Ab[0][row * 260 + col] = cvt4(v[it]);
    }
    #pragma unroll
    for (int it = 0; it < 8; ++it) v[it] = bp[2048 + it * 256 + t];
    __syncthreads();

    int wave = t >> 6, lane = t & 63, q = lane >> 4, m16 = lane & 15;
    int colbase = wave * 64;        // waves split the 256 output cols
    float sacc = 0.f;
    float iv_s = ini_l[t];
    int cur = 0;

    for (int jt = 0; jt < 4; ++jt) {
        // 1) write already-arrived tile jt+1 into the other buffer
        if (jt < 3) {
            #pragma unroll
            for (int it = 0; it < 8; ++it) {
                int idx = it * 256 + t;
                int row = idx >> 6, col = (idx & 63) * 4;
                *(u16x4*)&Ab[cur ^ 1][row * 260 + col] = cvt4(v[it]);
            }
        }
        // 2) issue loads for tile jt+2 (they land during the compute below)
        if (jt < 2) {
            #pragma unroll
            for (int it = 0; it < 8; ++it) v[it] = bp[(size_t)(jt + 2) * 2048 + it * 256 + t];
        }

        // 3) MFMA on Ab[cur]
        f32x4 acc[2][4];
        #pragma unroll
        for (int rt = 0; rt < 2; ++rt)
            #pragma unroll
            for (int ct = 0; ct < 4; ++ct)
                acc[rt][ct] = (f32x4){0.f, 0.f, 0.f, 0.f};

        const unsigned short* Abc = Ab[cur];
        #pragma unroll
        for (int ks = 0; ks < 8; ++ks) {
            bf16x8 afr[2];
            #pragma unroll
            for (int rt = 0; rt < 2; ++rt) {
                const unsigned short* p = &Abc[(rt * 16 + m16) * 260 + ks * 32 + q * 8];
                s16x4 a0 = *(const s16x4*)p;
                s16x4 a1 = *(const s16x4*)(p + 4);
                s16x8 sv = __builtin_shufflevector(a0, a1, 0, 1, 2, 3, 4, 5, 6, 7);
                afr[rt] = __builtin_bit_cast(bf16x8, sv);
            }
            #pragma unroll
            for (int ct = 0; ct < 4; ++ct) {
                const unsigned short* wp = WT + (colbase + ct * 16 + m16) * H + ks * 32 + q * 8;
                bf16x8 bfr = __builtin_bit_cast(bf16x8, *(const s16x8*)wp);
                #pragma unroll
                for (int rt = 0; rt < 2; ++rt)
                    acc[rt][ct] = __builtin_amdgcn_mfma_f32_16x16x32_bf16(afr[rt], bfr, acc[rt][ct], 0, 0, 0);
            }
        }

        // epilogue: hidden = relu(acc + base[k] + xw[b,j,k]); sacc += hidden*w_score[k]
        const float* xwp = xw + ((size_t)(b * NN) + jt * 32) * H;
        #pragma unroll
        for (int rt = 0; rt < 2; ++rt) {
            #pragma unroll
            for (int ct = 0; ct < 4; ++ct) {
                int k = colbase + ct * 16 + m16;
                float bs = base_l[k], wv = wsc_l[k];
                #pragma unroll
                for (int r = 0; r < 4; ++r) {
                    int jl = rt * 16 + q * 4 + r;      // C/D: row = quad*4+reg
                    float hv = acc[rt][ct][r] + bs + xwp[jl * H + k];
                    sacc += fmaxf(hv, 0.f) * wv;
                }
            }
        }

        // atom_pair writes for this tile (nontemporal: write-once stream)
        const f32x4* inb4  = (const f32x4*)(inp + ((size_t)(b * NN) + jt * 32) * H);
        f32x4*       pout4 = (f32x4*)(out_pair + ((size_t)bi * NN + jt * 32) * H);
        const f32x4* ini4  = (const f32x4*)ini_l;
        #pragma unroll
        for (int it = 0; it < 8; ++it) {
            int idx = it * 256 + t;
            f32x4 pv = inb4[idx];
            pv += ini4[idx & 63];
            __builtin_nontemporal_store(pv, &pout4[idx]);
        }

        __syncthreads();
        cur ^= 1;
    }

    // final S reduction (once per block, covers all 128 j)
    #pragma unroll
    for (int m = 1; m < 64; m <<= 1) sacc += __shfl_xor(sacc, m, 64);
    if (lane == 0) wred[wave] = sacc;
    __syncthreads();
    if (t == 0) wred[0] = wred[0] + wred[1] + wred[2] + wred[3] + 128.0f * b_score[0];
    __syncthreads();
    out_ctx[bi * H + t] = iv_s * wred[0];
}

extern "C" void kernel_launch(void* const* d_in, const int* in_sizes, int n_in,
                              void* d_out, int out_size, void* d_ws, size_t ws_size,
                              hipStream_t stream) {
    const float* inp     = (const float*)d_in[0];   // [16,128,256]
    const float* binf    = (const float*)d_in[1];   // [16,128,128,256]
    const float* W_atom  = (const float*)d_in[2];   // [256,256]
    const float* W_bin   = (const float*)d_in[3];   // [256,256]
    const float* b_bin   = (const float*)d_in[4];   // [256]
    const float* w_score = (const float*)d_in[5];   // [256]
    const float* b_score = (const float*)d_in[6];   // [1]

    float* out_ctx  = (float*)d_out;                 // [16,128,256]
    float* out_pair = (float*)d_out + BB * NN * H;   // [16,128,128,256]

    float* xw = (float*)d_ws;                                        // 2 MB
    unsigned short* WT = (unsigned short*)((char*)d_ws + (size_t)BB * NN * H * 4);

    k_prep_w<<<H, H, 0, stream>>>(W_bin, WT);
    k_xw<<<BB * NN / 8, H, 0, stream>>>(inp, W_atom, xw);
    k_main<<<BB * NN, 256, 0, stream>>>(inp, binf, xw, WT, b_bin, w_score,
                                        b_score, out_ctx, out_pair);
}